// Round 3
// baseline (457.287 us; speedup 1.0000x reference)
//
#include <hip/hip_runtime.h>

// ============================================================================
// CharLevelEncoder R8: pin W_hh' fragments into AGPRs -> kill scratch spills.
// R6/R7 evidence: WRITE ~182 MB vs 33.5 MB program writes; only scratch can
// write HBM from k_main. Arch-VGPR count stuck at 128 across R5-R7: the
// compiler keeps wreg (64 longs = 128 regs) in ARCH VGPRs and spills the
// per-step working set. CDNA MFMA A/B operands can source from AGPRs
// (cdna4_isa §10), so wreg belongs in the AGPR half of the unified file:
//   asm volatile("" : "+a"(wreg[kb][nt]))  at the def point.
// Budget @2 waves/SIMD (waves_per_eu(2,2)): 128 acc (wreg) + ~16 acc (mfma
// accs) + ~110 arch = ~250 <= 256. No other changes vs R7 (verified).
// ============================================================================

#define NW 32768

typedef __attribute__((ext_vector_type(8))) short short8;
typedef __attribute__((ext_vector_type(4))) float f32x4;
typedef __attribute__((ext_vector_type(4))) int i32x4;
typedef __attribute__((ext_vector_type(4))) unsigned short u16x4;

#define MFMA16(a,b,c) __builtin_amdgcn_mfma_f32_16x16x32_bf16(a,b,c,0,0,0)
#define MFMAI8(a,b,c) __builtin_amdgcn_mfma_i32_16x16x32_i8(a,b,c,0,0,0)

// ---- workspace layout (bytes) ----
#define O_ORDER 0           // i32[32768] sorted word ids (asc len)
#define O_SLEN  131072      // i32[32768] sorted lengths
#define O_WPK   262144      // i8 packed W_hh' fragments (262144)
#define O_USTP  524288      // f32[1024] u' = rowmax(whh)/(127*127)
#define O_WLIN  528384      // bf16 packed W_lin fragments (262144)
#define O_PX    790528      // bf16[256][256][4] x-proj+bias table (524288)
#define O_BH    1314816     // i32[128][16] per-block length histograms
#define O_BASE  1323008     // i32[128][16] scatter bases
// total 1331200 B

__device__ inline unsigned short f2b(float f) {   // fp32 -> bf16 RNE
  unsigned u = __builtin_bit_cast(unsigned, f);
  u = u + 0x7fffu + ((u >> 16) & 1u);
  return (unsigned short)(u >> 16);
}
__device__ inline float b2f(unsigned short u) {
  return __builtin_bit_cast(float, ((unsigned)u) << 16);
}
__device__ inline float fsigm(float x) {
  float e = __builtin_amdgcn_exp2f(-1.44269504f * x);
  return __builtin_amdgcn_rcpf(1.0f + e);
}
__device__ inline float ftanh(float x) {
  float e = __builtin_amdgcn_exp2f(2.88539008f * x);
  return 1.0f - 2.0f * __builtin_amdgcn_rcpf(e + 1.0f);
}

// ---- prep0: per-row scales over W_hh only (x-path is exact) ----
__global__ void k_prep0(const float* __restrict__ whh, unsigned char* __restrict__ ws) {
  int i = blockIdx.x * 256 + threadIdx.x;      // 0..1023
  const f32x4* r4 = (const f32x4*)(whh + i * 256);
  float mx = 0.f;
  #pragma unroll 8
  for (int k4 = 0; k4 < 64; ++k4) {
    f32x4 v = r4[k4];
    mx = fmaxf(mx, fmaxf(fmaxf(fabsf(v[0]), fabsf(v[1])),
                         fmaxf(fabsf(v[2]), fabsf(v[3]))));
  }
  ((float*)(ws + O_USTP))[i] = mx / (127.f * 127.f);
}

// ---- prep1: pack W_hh' i8 fragments + W_lin bf16 fragments ----
__global__ void k_prep1(const float* __restrict__ whh, const float* __restrict__ wlin,
                        unsigned char* __restrict__ ws) {
  int i = blockIdx.x * 256 + threadIdx.x;
  if (i < 262144) {
    int j = i & 7, lane = (i >> 3) & 63, t2 = i >> 9;
    int nt = t2 & 7, u2 = t2 >> 3;
    int kb = u2 & 7, w = u2 >> 3;
    int n = (nt >> 1) * 256 + w * 32 + (nt & 1) * 16 + (lane & 15);
    int k = kb * 32 + (lane >> 4) * 8 + j;
    float v = whh[n * 256 + k];
    float ustep = ((const float*)(ws + O_USTP))[n] * 127.f;   // rowmax/127
    float qf = (ustep > 0.f) ? v / ustep : 0.f;
    int q = (int)__builtin_rintf(qf);
    q = q < -127 ? -127 : (q > 127 ? 127 : q);
    ((signed char*)(ws + O_WPK))[i] = (signed char)q;
    return;
  }
  int i2 = i - 262144;                  // < 131072, W_lin pack (verified R4)
  {
    int j = i2 & 7, lane = (i2 >> 3) & 63, t3 = i2 >> 9;
    int kf = t3 & 15, nn = t3 >> 4;
    int n = (nn >> 2) * 64 + (nn & 3) * 16 + (lane & 15);
    int k = kf * 32 + (lane >> 4) * 8 + j;
    ((unsigned short*)(ws + O_WLIN))[i2] = f2b(wlin[n * 512 + k]);
  }
}

// ---- prep2: PX[c][hd][g] = sum_k wih[g*256+hd][k]*ech[c][k] + bih+bhh (bf16) ----
__global__ void k_prep2(const float* __restrict__ wih, const float* __restrict__ ech,
                        const float* __restrict__ bih, const float* __restrict__ bhh,
                        unsigned char* __restrict__ ws) {
  int id = blockIdx.x * 256 + threadIdx.x;     // 0..262143
  int c = id >> 10, n = id & 1023;
  const f32x4* w4 = (const f32x4*)(wih + n * 64);
  const f32x4* e4 = (const f32x4*)(ech + c * 64);
  float acc = bih[n] + bhh[n];
  #pragma unroll
  for (int k4 = 0; k4 < 16; ++k4) {
    f32x4 a = w4[k4], e = e4[k4];
    acc += a[0] * e[0] + a[1] * e[1] + a[2] * e[2] + a[3] * e[3];
  }
  ((unsigned short*)(ws + O_PX))[((c << 8) + (n & 255)) * 4 + (n >> 8)] = f2b(acc);
}

// ---- multi-block counting sort by length: hist -> scan -> scatter ----
__global__ void k_hist(const int* __restrict__ lens, unsigned char* __restrict__ ws) {
  __shared__ int h[16];
  int t = threadIdx.x, b = blockIdx.x;
  if (t < 16) h[t] = 0;
  __syncthreads();
  int wid = b * 256 + t;
  int l = lens[wid]; l = l < 1 ? 1 : (l > 16 ? 16 : l);
  atomicAdd(&h[l - 1], 1);
  __syncthreads();
  if (t < 16) ((int*)(ws + O_BH))[b * 16 + t] = h[t];
}

__global__ void k_scan(unsigned char* __restrict__ ws) {
  __shared__ int tot[16], g[16];
  int t = threadIdx.x;
  const int* bh = (const int*)(ws + O_BH);
  int* base = (int*)(ws + O_BASE);
  if (t < 16) {
    int s = 0;
    for (int b = 0; b < 128; ++b) s += bh[b * 16 + t];
    tot[t] = s;
  }
  __syncthreads();
  if (t == 0) { int a = 0; for (int i = 0; i < 16; ++i) { g[i] = a; a += tot[i]; } }
  __syncthreads();
  if (t < 16) {
    int run = g[t];
    for (int b = 0; b < 128; ++b) { base[b * 16 + t] = run; run += bh[b * 16 + t]; }
  }
}

__global__ void k_scatter(const int* __restrict__ lens, unsigned char* __restrict__ ws) {
  __shared__ int cnt[16];
  int t = threadIdx.x, b = blockIdx.x;
  if (t < 16) cnt[t] = 0;
  __syncthreads();
  int wid = b * 256 + t;
  int l = lens[wid]; l = l < 1 ? 1 : (l > 16 ? 16 : l);
  int rank = atomicAdd(&cnt[l - 1], 1);
  int p = ((const int*)(ws + O_BASE))[b * 16 + (l - 1)] + rank;
  ((int*)(ws + O_ORDER))[p] = wid;
  ((int*)(ws + O_SLEN))[p] = l;
}

// ---- main persistent kernel: 256 blocks x 512 threads, 2 waves/SIMD ----
__global__ __launch_bounds__(512)
__attribute__((amdgpu_waves_per_eu(2, 2)))
void k_main(
    const int* __restrict__ cidx, const float* __restrict__ wemb,
    const float* __restrict__ blin, float* __restrict__ outp,
    const unsigned char* __restrict__ ws) {
  // Xb: double-buffered h-state, i8. [buf][mt][kb][lane][8]
  __shared__ signed char Xb[2][4][8][64][8];   // 32 KB
  __shared__ int CW[64][16];                   //  4 KB

  const int tid = threadIdx.x, b = blockIdx.x;
  const int w = tid >> 6, lane = tid & 63;
  const int q = lane >> 4, l15 = lane & 15;

  const int* order = (const int*)(ws + O_ORDER);
  const int* slen  = (const int*)(ws + O_SLEN);
  const signed char* wpk = (const signed char*)(ws + O_WPK);
  const float* upt = (const float*)(ws + O_USTP);
  const unsigned short* wlin = (const unsigned short*)(ws + O_WLIN);
  const unsigned short* pxt = (const unsigned short*)(ws + O_PX);

  // ---- prologue: all of W_hh' -> AGPRs (128 regs), scales ----
  long wreg[8][8];
  #pragma unroll
  for (int kb = 0; kb < 8; ++kb)
    #pragma unroll
    for (int nt = 0; nt < 8; ++nt) {
      wreg[kb][nt] = *(const long*)(wpk + (((w * 8 + kb) * 8 + nt) * 64 + lane) * 8);
      // Pin to the AGPR half of the unified file: MFMA B-operand can source
      // AGPRs directly (cdna4_isa §10), and this frees ~128 arch VGPRs that
      // R5-R7 were burning, forcing creg/hreg/temps into scratch (~150 MB
      // of HBM round-trips per dispatch).
      asm volatile("" : "+a"(wreg[kb][nt]));
    }

  float uq[8];
  #pragma unroll
  for (int nt = 0; nt < 8; ++nt) {
    int n = (nt >> 1) * 256 + w * 32 + (nt & 1) * 16 + l15;
    uq[nt] = upt[n];
  }
  const int hd0 = w * 32 + l15;          // hdim at hs=0 (hs adds +16)
  const int mh = w >> 2, nw = w & 3;
  float blv[4];
  #pragma unroll
  for (int nt = 0; nt < 4; ++nt) blv[nt] = blin[nw * 64 + nt * 16 + l15];

  // ---- two balanced slices: {b, 511-b} ----
  for (int sl = 0; sl < 2; ++sl) {
    const int s = sl ? (511 - b) : b;
    const int base = 64 * s;
    __syncthreads();                    // prev epilogue's Xb reads done
    { // zero Xb buf0 h-state (16 KB)
      long* p = (long*)&Xb[0][0][0][0][0];
      #pragma unroll
      for (int ii = 0; ii < 4; ++ii) p[tid + 512 * ii] = 0L;
    }
    if (tid < 256) {                    // this slice's char indices (streamed once)
      int m = tid >> 2, part = tid & 3;
      int wid = order[base + m];
      *(i32x4*)&CW[m][part * 4] =
          __builtin_nontemporal_load((const i32x4*)(cidx + wid * 16 + part * 4));
    }
    int tmax[4]; unsigned lenpk[4];
    #pragma unroll
    for (int mt = 0; mt < 4; ++mt) {
      int pbm = base + 16 * mt;
      tmax[mt] = slen[pbm + 15];
      unsigned l0 = (unsigned)slen[pbm + q * 4 + 0];
      unsigned l1 = (unsigned)slen[pbm + q * 4 + 1];
      unsigned l2 = (unsigned)slen[pbm + q * 4 + 2];
      unsigned l3 = (unsigned)slen[pbm + q * 4 + 3];
      lenpk[mt] = l0 | (l1 << 8) | (l2 << 16) | (l3 << 24);
    }
    const int Tm = tmax[3];
    __syncthreads();                    // CW + zeroing visible

    float creg[4][2][4];
    unsigned hreg[4][2];
    #pragma unroll
    for (int mt = 0; mt < 4; ++mt)
      #pragma unroll
      for (int hs = 0; hs < 2; ++hs) {
        hreg[mt][hs] = 0u;
        #pragma unroll
        for (int r = 0; r < 4; ++r) creg[mt][hs][r] = 0.f;
      }

    for (int t = 0; t < Tm; ++t) {
      const int rd = t & 1, wb = rd ^ 1;
      #pragma unroll
      for (int mt = 0; mt < 4; ++mt) {
        if (mt != 3 && t >= tmax[mt]) continue;   // wave-uniform
        int cc[4];
        #pragma unroll
        for (int r = 0; r < 4; ++r) cc[r] = CW[mt * 16 + q * 4 + r][t] & 255;
        #pragma unroll
        for (int hs = 0; hs < 2; ++hs) {
          u16x4 pb[4];
          #pragma unroll
          for (int r = 0; r < 4; ++r)
            pb[r] = *(const u16x4*)&pxt[((cc[r] << 8) + hd0 + hs * 16) * 4];
          i32x4 a0 = (i32x4)0, a1 = (i32x4)0, a2 = (i32x4)0, a3 = (i32x4)0;
          #pragma unroll
          for (int kb = 0; kb < 8; ++kb) {
            long A = *(const long*)&Xb[rd][mt][kb][lane][0];
            a0 = MFMAI8(A, wreg[kb][0 + hs], a0);
            a1 = MFMAI8(A, wreg[kb][2 + hs], a1);
            a2 = MFMAI8(A, wreg[kb][4 + hs], a2);
            a3 = MFMAI8(A, wreg[kb][6 + hs], a3);
          }
          // gates + LSTM update; C-layout row(word) = q*4+r, col(n) = l15
          unsigned hp = 0;
          #pragma unroll
          for (int r = 0; r < 4; ++r) {
            float gi = (float)a0[r] * uq[0 + hs] + b2f(pb[r][0]);
            float gf = (float)a1[r] * uq[2 + hs] + b2f(pb[r][1]);
            float gg = (float)a2[r] * uq[4 + hs] + b2f(pb[r][2]);
            float go = (float)a3[r] * uq[6 + hs] + b2f(pb[r][3]);
            float si = fsigm(gi), sf = fsigm(gf);
            float sg = ftanh(gg), so = fsigm(go);
            float cold = creg[mt][hs][r];
            float cn = sf * cold + si * sg;
            float hn = so * ftanh(cn);
            int lene = (int)((lenpk[mt] >> (8 * r)) & 255u);
            bool live = t < lene;
            creg[mt][hs][r] = live ? cn : cold;
            int hq = (int)__builtin_rintf(127.f * hn);   // |hn|<1 -> no clamp
            unsigned ob = (hreg[mt][hs] >> (8 * r)) & 255u;
            unsigned nb = live ? ((unsigned)hq & 255u) : ob;
            hp |= nb << (8 * r);
          }
          hreg[mt][hs] = hp;
        }
      } // mt

      // h write-back into the OTHER buffer (always-write; wave w owns kb = w)
      #pragma unroll
      for (int mt = 0; mt < 4; ++mt) {
        if (mt != 3 && t >= tmax[mt]) continue;
        #pragma unroll
        for (int hs = 0; hs < 2; ++hs) {
          int row16 = 16 * (hs * 2 + (l15 >> 3));
          #pragma unroll
          for (int r = 0; r < 4; ++r)
            Xb[wb][mt][w][(q * 4 + r) + row16][l15 & 7] =
                (signed char)((hreg[mt][hs] >> (8 * r)) & 255u);
        }
      }
      __syncthreads();                  // single barrier per step
    } // t

    // ---- fused final linear for this slice (bf16 MFMA) ----
    int widA[2];
    #pragma unroll
    for (int mi = 0; mi < 2; ++mi) widA[mi] = order[base + (2 * mh + mi) * 16 + l15];
    const int tb0 = (mh ? tmax[2] : tmax[0]) & 1;   // buffer holding final h
    const int tb1 = (mh ? tmax[3] : tmax[1]) & 1;
    f32x4 fac[2][4];
    #pragma unroll
    for (int mi = 0; mi < 2; ++mi)
      #pragma unroll
      for (int nt = 0; nt < 4; ++nt) fac[mi][nt] = 0.0f;

    #pragma unroll
    for (int kf = 0; kf < 16; ++kf) {
      short8 Bn[4];
      #pragma unroll
      for (int nt = 0; nt < 4; ++nt)
        Bn[nt] = ((const short8*)wlin)[((nw * 4 + nt) * 16 + kf) * 64 + lane];
      short8 Am[2];
      #pragma unroll
      for (int mi = 0; mi < 2; ++mi) {
        if (kf < 8) {                   // word_emb fp32 -> bf16 (streamed once)
          const f32x4* pa = (const f32x4*)(wemb + widA[mi] * 256 + kf * 32 + q * 8);
          f32x4 f0 = __builtin_nontemporal_load(pa);
          f32x4 f1 = __builtin_nontemporal_load(pa + 1);
          short8 A;
          A[0] = (short)f2b(f0[0]); A[1] = (short)f2b(f0[1]);
          A[2] = (short)f2b(f0[2]); A[3] = (short)f2b(f0[3]);
          A[4] = (short)f2b(f1[0]); A[5] = (short)f2b(f1[1]);
          A[6] = (short)f2b(f1[2]); A[7] = (short)f2b(f1[3]);
          Am[mi] = A;
        } else {                        // final h from Xb i8 -> bf16
          int mtv = 2 * mh + mi;
          int tb = mi ? tb1 : tb0;
          long ch = *(const long*)&Xb[tb][mtv][kf - 8][lane][0];
          short8 A;
          #pragma unroll
          for (int j = 0; j < 8; ++j) {
            int v = (int)(signed char)((ch >> (8 * j)) & 255);
            A[j] = (short)f2b((float)v * (1.f / 127.f));
          }
          Am[mi] = A;
        }
      }
      #pragma unroll
      for (int mi = 0; mi < 2; ++mi)
        #pragma unroll
        for (int nt = 0; nt < 4; ++nt)
          fac[mi][nt] = MFMA16(Am[mi], Bn[nt], fac[mi][nt]);
    }
    #pragma unroll
    for (int mi = 0; mi < 2; ++mi) {
      #pragma unroll
      for (int r = 0; r < 4; ++r) {
        int wid = order[base + (2 * mh + mi) * 16 + q * 4 + r];
        float* po = outp + wid * 256 + nw * 64 + l15;
        #pragma unroll
        for (int nt = 0; nt < 4; ++nt) {
          float v = fac[mi][nt][r] + blv[nt];
          __builtin_nontemporal_store(v > 0.f ? v : 0.f, po + nt * 16);
        }
      }
    }
  } // slice
}

extern "C" void kernel_launch(void* const* d_in, const int* in_sizes, int n_in,
                              void* d_out, int out_size, void* d_ws, size_t ws_size,
                              hipStream_t stream) {
  const int*   cidx = (const int*)d_in[0];
  const int*   clen = (const int*)d_in[1];
  const float* wemb = (const float*)d_in[2];
  const float* ech  = (const float*)d_in[3];
  const float* wih  = (const float*)d_in[4];
  const float* whh  = (const float*)d_in[5];
  const float* bih  = (const float*)d_in[6];
  const float* bhh  = (const float*)d_in[7];
  const float* wlin = (const float*)d_in[8];
  const float* blin = (const float*)d_in[9];
  float* outp = (float*)d_out;
  unsigned char* ws = (unsigned char*)d_ws;

  k_prep0<<<4, 256, 0, stream>>>(whh, ws);
  k_prep1<<<1536, 256, 0, stream>>>(whh, wlin, ws);
  k_prep2<<<1024, 256, 0, stream>>>(wih, ech, bih, bhh, ws);
  k_hist<<<128, 256, 0, stream>>>(clen, ws);
  k_scan<<<1, 64, 0, stream>>>(ws);
  k_scatter<<<128, 256, 0, stream>>>(clen, ws);
  k_main<<<256, 512, 0, stream>>>(cidx, wemb, blin, outp, ws);
}

// Round 4
// 399.103 us; speedup vs baseline: 1.1458x; 1.1458x over previous
//
#include <hip/hip_runtime.h>

// ============================================================================
// CharLevelEncoder R9: cut register demand below the 256 budget (no scratch).
// R5-R8 unified post-mortem: at 2 waves/SIMD the unified file = 256 regs/wave
// (128 arch + 128 acc as reported). Total demand was ~260-290 (wreg 128 +
// creg 32 + working set) -> overflow past AGPR-spill into MEMORY scratch:
// the ~140-170 MB symmetric FETCH/WRITE excess at ~60 B/thread/step.
// Attributes can't fix genuine over-demand; structure can:
//  - wreg = kb 0-3 only (64 VGPRs); kb 4-7 in LDS (128 KB), B-fragments
//    ds_read_b64 per use (~16/wave per (mt,hs) - cheap on the LDS pipe).
//  - Xb single-buffered (16 KB), 2 barriers/step; dead words skip write.
//  - A-fragments hoisted once per mt (used by both hs).
// New total ~190 <= 256, slack ~60 -> zero memory scratch.
// LDS 148 KB dynamic -> 1 block/CU. Everything else = R7 (verified).
// ============================================================================

#define NW 32768

typedef __attribute__((ext_vector_type(8))) short short8;
typedef __attribute__((ext_vector_type(4))) float f32x4;
typedef __attribute__((ext_vector_type(4))) int i32x4;
typedef __attribute__((ext_vector_type(4))) unsigned short u16x4;

#define MFMA16(a,b,c) __builtin_amdgcn_mfma_f32_16x16x32_bf16(a,b,c,0,0,0)
#define MFMAI8(a,b,c) __builtin_amdgcn_mfma_i32_16x16x32_i8(a,b,c,0,0,0)

// ---- workspace layout (bytes) ----
#define O_ORDER 0           // i32[32768] sorted word ids (asc len)
#define O_SLEN  131072      // i32[32768] sorted lengths
#define O_WPK   262144      // i8 packed W_hh' fragments (262144)
#define O_USTP  524288      // f32[1024] u' = rowmax(whh)/(127*127)
#define O_WLIN  528384      // bf16 packed W_lin fragments (262144)
#define O_PX    790528      // bf16[256][256][4] x-proj+bias table (524288)
#define O_BH    1314816     // i32[128][16] per-block length histograms
#define O_BASE  1323008     // i32[128][16] scatter bases
// total 1331200 B

__device__ inline unsigned short f2b(float f) {   // fp32 -> bf16 RNE
  unsigned u = __builtin_bit_cast(unsigned, f);
  u = u + 0x7fffu + ((u >> 16) & 1u);
  return (unsigned short)(u >> 16);
}
__device__ inline float b2f(unsigned short u) {
  return __builtin_bit_cast(float, ((unsigned)u) << 16);
}
__device__ inline float fsigm(float x) {
  float e = __builtin_amdgcn_exp2f(-1.44269504f * x);
  return __builtin_amdgcn_rcpf(1.0f + e);
}
__device__ inline float ftanh(float x) {
  float e = __builtin_amdgcn_exp2f(2.88539008f * x);
  return 1.0f - 2.0f * __builtin_amdgcn_rcpf(e + 1.0f);
}

// ---- prep0: per-row scales over W_hh only (x-path is exact) ----
__global__ void k_prep0(const float* __restrict__ whh, unsigned char* __restrict__ ws) {
  int i = blockIdx.x * 256 + threadIdx.x;      // 0..1023
  const f32x4* r4 = (const f32x4*)(whh + i * 256);
  float mx = 0.f;
  #pragma unroll 8
  for (int k4 = 0; k4 < 64; ++k4) {
    f32x4 v = r4[k4];
    mx = fmaxf(mx, fmaxf(fmaxf(fabsf(v[0]), fabsf(v[1])),
                         fmaxf(fabsf(v[2]), fabsf(v[3]))));
  }
  ((float*)(ws + O_USTP))[i] = mx / (127.f * 127.f);
}

// ---- prep1: pack W_hh' i8 fragments + W_lin bf16 fragments ----
__global__ void k_prep1(const float* __restrict__ whh, const float* __restrict__ wlin,
                        unsigned char* __restrict__ ws) {
  int i = blockIdx.x * 256 + threadIdx.x;
  if (i < 262144) {
    int j = i & 7, lane = (i >> 3) & 63, t2 = i >> 9;
    int nt = t2 & 7, u2 = t2 >> 3;
    int kb = u2 & 7, w = u2 >> 3;
    int n = (nt >> 1) * 256 + w * 32 + (nt & 1) * 16 + (lane & 15);
    int k = kb * 32 + (lane >> 4) * 8 + j;
    float v = whh[n * 256 + k];
    float ustep = ((const float*)(ws + O_USTP))[n] * 127.f;   // rowmax/127
    float qf = (ustep > 0.f) ? v / ustep : 0.f;
    int q = (int)__builtin_rintf(qf);
    q = q < -127 ? -127 : (q > 127 ? 127 : q);
    ((signed char*)(ws + O_WPK))[i] = (signed char)q;
    return;
  }
  int i2 = i - 262144;                  // < 131072, W_lin pack (verified R4)
  {
    int j = i2 & 7, lane = (i2 >> 3) & 63, t3 = i2 >> 9;
    int kf = t3 & 15, nn = t3 >> 4;
    int n = (nn >> 2) * 64 + (nn & 3) * 16 + (lane & 15);
    int k = kf * 32 + (lane >> 4) * 8 + j;
    ((unsigned short*)(ws + O_WLIN))[i2] = f2b(wlin[n * 512 + k]);
  }
}

// ---- prep2: PX[c][hd][g] = sum_k wih[g*256+hd][k]*ech[c][k] + bih+bhh (bf16) ----
__global__ void k_prep2(const float* __restrict__ wih, const float* __restrict__ ech,
                        const float* __restrict__ bih, const float* __restrict__ bhh,
                        unsigned char* __restrict__ ws) {
  int id = blockIdx.x * 256 + threadIdx.x;     // 0..262143
  int c = id >> 10, n = id & 1023;
  const f32x4* w4 = (const f32x4*)(wih + n * 64);
  const f32x4* e4 = (const f32x4*)(ech + c * 64);
  float acc = bih[n] + bhh[n];
  #pragma unroll
  for (int k4 = 0; k4 < 16; ++k4) {
    f32x4 a = w4[k4], e = e4[k4];
    acc += a[0] * e[0] + a[1] * e[1] + a[2] * e[2] + a[3] * e[3];
  }
  ((unsigned short*)(ws + O_PX))[((c << 8) + (n & 255)) * 4 + (n >> 8)] = f2b(acc);
}

// ---- multi-block counting sort by length: hist -> scan -> scatter ----
__global__ void k_hist(const int* __restrict__ lens, unsigned char* __restrict__ ws) {
  __shared__ int h[16];
  int t = threadIdx.x, b = blockIdx.x;
  if (t < 16) h[t] = 0;
  __syncthreads();
  int wid = b * 256 + t;
  int l = lens[wid]; l = l < 1 ? 1 : (l > 16 ? 16 : l);
  atomicAdd(&h[l - 1], 1);
  __syncthreads();
  if (t < 16) ((int*)(ws + O_BH))[b * 16 + t] = h[t];
}

__global__ void k_scan(unsigned char* __restrict__ ws) {
  __shared__ int tot[16], g[16];
  int t = threadIdx.x;
  const int* bh = (const int*)(ws + O_BH);
  int* base = (int*)(ws + O_BASE);
  if (t < 16) {
    int s = 0;
    for (int b = 0; b < 128; ++b) s += bh[b * 16 + t];
    tot[t] = s;
  }
  __syncthreads();
  if (t == 0) { int a = 0; for (int i = 0; i < 16; ++i) { g[i] = a; a += tot[i]; } }
  __syncthreads();
  if (t < 16) {
    int run = g[t];
    for (int b = 0; b < 128; ++b) { base[b * 16 + t] = run; run += bh[b * 16 + t]; }
  }
}

__global__ void k_scatter(const int* __restrict__ lens, unsigned char* __restrict__ ws) {
  __shared__ int cnt[16];
  int t = threadIdx.x, b = blockIdx.x;
  if (t < 16) cnt[t] = 0;
  __syncthreads();
  int wid = b * 256 + t;
  int l = lens[wid]; l = l < 1 ? 1 : (l > 16 ? 16 : l);
  int rank = atomicAdd(&cnt[l - 1], 1);
  int p = ((const int*)(ws + O_BASE))[b * 16 + (l - 1)] + rank;
  ((int*)(ws + O_ORDER))[p] = wid;
  ((int*)(ws + O_SLEN))[p] = l;
}

// ---- main persistent kernel: 256 blocks x 512 threads, 148 KB LDS ----
__global__ __launch_bounds__(512)
__attribute__((amdgpu_waves_per_eu(2, 2)))
void k_main(
    const int* __restrict__ cidx, const float* __restrict__ wemb,
    const float* __restrict__ blin, float* __restrict__ outp,
    const unsigned char* __restrict__ ws) {
  extern __shared__ signed char smem[];
  // WL: W_hh' kb 4-7 fragments [kb4][w][nt][lane][8]  128 KB
  signed char (*WL)[8][8][64][8] = (signed char (*)[8][8][64][8])smem;
  // Xb: single-buffered h-state, i8 [mt][kb][lane][8]  16 KB
  signed char (*Xb)[8][64][8] = (signed char (*)[8][64][8])(smem + 131072);
  int (*CW)[16] = (int (*)[16])(smem + 131072 + 16384);   // 4 KB

  const int tid = threadIdx.x, b = blockIdx.x;
  const int w = tid >> 6, lane = tid & 63;
  const int q = lane >> 4, l15 = lane & 15;

  const int* order = (const int*)(ws + O_ORDER);
  const int* slen  = (const int*)(ws + O_SLEN);
  const signed char* wpk = (const signed char*)(ws + O_WPK);
  const float* upt = (const float*)(ws + O_USTP);
  const unsigned short* wlin = (const unsigned short*)(ws + O_WLIN);
  const unsigned short* pxt = (const unsigned short*)(ws + O_PX);

  // ---- prologue: W kb0-3 -> VGPR (64 regs); W kb4-7 -> LDS (128 KB) ----
  long wreg[4][8];
  #pragma unroll
  for (int kb = 0; kb < 4; ++kb)
    #pragma unroll
    for (int nt = 0; nt < 8; ++nt)
      wreg[kb][nt] = *(const long*)(wpk + (((w * 8 + kb) * 8 + nt) * 64 + lane) * 8);

  {
    long* wlds = (long*)smem;
    const long* wsrc = (const long*)wpk;
    #pragma unroll
    for (int ii = 0; ii < 32; ++ii) {
      int f = ii * 512 + tid;            // 0..16383 == WL flat long index
      int lane_ = f & 63, r = f >> 6;
      int nt_ = r & 7, r2 = r >> 3;
      int w_ = r2 & 7, kb4 = r2 >> 3;
      wlds[f] = wsrc[((w_ * 8 + 4 + kb4) * 8 + nt_) * 64 + lane_];
    }
  }

  float uq[8];
  #pragma unroll
  for (int nt = 0; nt < 8; ++nt) {
    int n = (nt >> 1) * 256 + w * 32 + (nt & 1) * 16 + l15;
    uq[nt] = upt[n];
  }
  const int hd0 = w * 32 + l15;          // hdim at hs=0 (hs adds +16)
  const int mh = w >> 2, nw = w & 3;
  float blv[4];
  #pragma unroll
  for (int nt = 0; nt < 4; ++nt) blv[nt] = blin[nw * 64 + nt * 16 + l15];

  // ---- two balanced slices: {b, 511-b} ----
  for (int sl = 0; sl < 2; ++sl) {
    const int s = sl ? (511 - b) : b;
    const int base = 64 * s;
    __syncthreads();                    // WL staged / prev epilogue done
    { // zero Xb h-state (16 KB)
      long* p = (long*)&Xb[0][0][0][0];
      #pragma unroll
      for (int ii = 0; ii < 4; ++ii) p[tid + 512 * ii] = 0L;
    }
    if (tid < 256) {                    // this slice's char indices (streamed once)
      int m = tid >> 2, part = tid & 3;
      int wid = order[base + m];
      *(i32x4*)&CW[m][part * 4] =
          __builtin_nontemporal_load((const i32x4*)(cidx + wid * 16 + part * 4));
    }
    int tmax[4]; unsigned lenpk[4];
    #pragma unroll
    for (int mt = 0; mt < 4; ++mt) {
      int pbm = base + 16 * mt;
      tmax[mt] = slen[pbm + 15];
      unsigned l0 = (unsigned)slen[pbm + q * 4 + 0];
      unsigned l1 = (unsigned)slen[pbm + q * 4 + 1];
      unsigned l2 = (unsigned)slen[pbm + q * 4 + 2];
      unsigned l3 = (unsigned)slen[pbm + q * 4 + 3];
      lenpk[mt] = l0 | (l1 << 8) | (l2 << 16) | (l3 << 24);
    }
    const int Tm = tmax[3];
    __syncthreads();                    // CW + zeroing visible

    float creg[4][2][4];
    unsigned hreg[4][2];
    #pragma unroll
    for (int mt = 0; mt < 4; ++mt)
      #pragma unroll
      for (int hs = 0; hs < 2; ++hs) {
        hreg[mt][hs] = 0u;
        #pragma unroll
        for (int r = 0; r < 4; ++r) creg[mt][hs][r] = 0.f;
      }

    for (int t = 0; t < Tm; ++t) {
      #pragma unroll
      for (int mt = 0; mt < 4; ++mt) {
        if (mt != 3 && t >= tmax[mt]) continue;   // wave-uniform
        long Ar[8];
        #pragma unroll
        for (int kb = 0; kb < 8; ++kb)
          Ar[kb] = *(const long*)&Xb[mt][kb][lane][0];
        int cc[4];
        #pragma unroll
        for (int r = 0; r < 4; ++r) cc[r] = CW[mt * 16 + q * 4 + r][t] & 255;
        #pragma unroll
        for (int hs = 0; hs < 2; ++hs) {
          u16x4 pb[4];
          #pragma unroll
          for (int r = 0; r < 4; ++r)
            pb[r] = *(const u16x4*)&pxt[((cc[r] << 8) + hd0 + hs * 16) * 4];
          i32x4 a0 = (i32x4)0, a1 = (i32x4)0, a2 = (i32x4)0, a3 = (i32x4)0;
          #pragma unroll
          for (int kb = 0; kb < 4; ++kb) {
            a0 = MFMAI8(Ar[kb], wreg[kb][0 + hs], a0);
            a1 = MFMAI8(Ar[kb], wreg[kb][2 + hs], a1);
            a2 = MFMAI8(Ar[kb], wreg[kb][4 + hs], a2);
            a3 = MFMAI8(Ar[kb], wreg[kb][6 + hs], a3);
          }
          #pragma unroll
          for (int kb = 4; kb < 8; ++kb) {        // B from LDS
            long b0 = *(const long*)&WL[kb - 4][w][0 + hs][lane][0];
            long b1 = *(const long*)&WL[kb - 4][w][2 + hs][lane][0];
            long b2 = *(const long*)&WL[kb - 4][w][4 + hs][lane][0];
            long b3 = *(const long*)&WL[kb - 4][w][6 + hs][lane][0];
            a0 = MFMAI8(Ar[kb], b0, a0);
            a1 = MFMAI8(Ar[kb], b1, a1);
            a2 = MFMAI8(Ar[kb], b2, a2);
            a3 = MFMAI8(Ar[kb], b3, a3);
          }
          // gates + LSTM update; C-layout row(word) = q*4+r, col(n) = l15
          unsigned hp = 0;
          #pragma unroll
          for (int r = 0; r < 4; ++r) {
            float gi = (float)a0[r] * uq[0 + hs] + b2f(pb[r][0]);
            float gf = (float)a1[r] * uq[2 + hs] + b2f(pb[r][1]);
            float gg = (float)a2[r] * uq[4 + hs] + b2f(pb[r][2]);
            float go = (float)a3[r] * uq[6 + hs] + b2f(pb[r][3]);
            float si = fsigm(gi), sf = fsigm(gf);
            float sg = ftanh(gg), so = fsigm(go);
            float cold = creg[mt][hs][r];
            float cn = sf * cold + si * sg;
            float hn = so * ftanh(cn);
            int lene = (int)((lenpk[mt] >> (8 * r)) & 255u);
            bool live = t < lene;
            creg[mt][hs][r] = live ? cn : cold;
            int hq = (int)__builtin_rintf(127.f * hn);   // |hn|<1 -> no clamp
            unsigned ob = (hreg[mt][hs] >> (8 * r)) & 255u;
            unsigned nb = live ? ((unsigned)hq & 255u) : ob;
            hp |= nb << (8 * r);
          }
          hreg[mt][hs] = hp;
        }
      } // mt
      __syncthreads();                  // all Xb reads of step t done

      // h write-back (single buffer; wave w owns h-chunk kb = w)
      #pragma unroll
      for (int mt = 0; mt < 4; ++mt) {
        if (mt != 3 && t >= tmax[mt]) continue;
        #pragma unroll
        for (int hs = 0; hs < 2; ++hs) {
          int row16 = 16 * (hs * 2 + (l15 >> 3));
          #pragma unroll
          for (int r = 0; r < 4; ++r)
            Xb[mt][w][(q * 4 + r) + row16][l15 & 7] =
                (signed char)((hreg[mt][hs] >> (8 * r)) & 255u);
        }
      }
      __syncthreads();                  // writes visible for step t+1
    } // t

    // ---- fused final linear for this slice (bf16 MFMA) ----
    int widA[2];
    #pragma unroll
    for (int mi = 0; mi < 2; ++mi) widA[mi] = order[base + (2 * mh + mi) * 16 + l15];
    f32x4 fac[2][4];
    #pragma unroll
    for (int mi = 0; mi < 2; ++mi)
      #pragma unroll
      for (int nt = 0; nt < 4; ++nt) fac[mi][nt] = 0.0f;

    #pragma unroll
    for (int kf = 0; kf < 16; ++kf) {
      short8 Bn[4];
      #pragma unroll
      for (int nt = 0; nt < 4; ++nt)
        Bn[nt] = ((const short8*)wlin)[((nw * 4 + nt) * 16 + kf) * 64 + lane];
      short8 Am[2];
      #pragma unroll
      for (int mi = 0; mi < 2; ++mi) {
        if (kf < 8) {                   // word_emb fp32 -> bf16 (streamed once)
          const f32x4* pa = (const f32x4*)(wemb + widA[mi] * 256 + kf * 32 + q * 8);
          f32x4 f0 = __builtin_nontemporal_load(pa);
          f32x4 f1 = __builtin_nontemporal_load(pa + 1);
          short8 A;
          A[0] = (short)f2b(f0[0]); A[1] = (short)f2b(f0[1]);
          A[2] = (short)f2b(f0[2]); A[3] = (short)f2b(f0[3]);
          A[4] = (short)f2b(f1[0]); A[5] = (short)f2b(f1[1]);
          A[6] = (short)f2b(f1[2]); A[7] = (short)f2b(f1[3]);
          Am[mi] = A;
        } else {                        // final h from Xb i8 -> bf16
          int mtv = 2 * mh + mi;
          long ch = *(const long*)&Xb[mtv][kf - 8][lane][0];
          short8 A;
          #pragma unroll
          for (int j = 0; j < 8; ++j) {
            int v = (int)(signed char)((ch >> (8 * j)) & 255);
            A[j] = (short)f2b((float)v * (1.f / 127.f));
          }
          Am[mi] = A;
        }
      }
      #pragma unroll
      for (int mi = 0; mi < 2; ++mi)
        #pragma unroll
        for (int nt = 0; nt < 4; ++nt)
          fac[mi][nt] = MFMA16(Am[mi], Bn[nt], fac[mi][nt]);
    }
    #pragma unroll
    for (int mi = 0; mi < 2; ++mi) {
      #pragma unroll
      for (int r = 0; r < 4; ++r) {
        int wid = order[base + (2 * mh + mi) * 16 + q * 4 + r];
        float* po = outp + wid * 256 + nw * 64 + l15;
        #pragma unroll
        for (int nt = 0; nt < 4; ++nt) {
          float v = fac[mi][nt][r] + blv[nt];
          __builtin_nontemporal_store(v > 0.f ? v : 0.f, po + nt * 16);
        }
      }
    }
  } // slice
}

extern "C" void kernel_launch(void* const* d_in, const int* in_sizes, int n_in,
                              void* d_out, int out_size, void* d_ws, size_t ws_size,
                              hipStream_t stream) {
  const int*   cidx = (const int*)d_in[0];
  const int*   clen = (const int*)d_in[1];
  const float* wemb = (const float*)d_in[2];
  const float* ech  = (const float*)d_in[3];
  const float* wih  = (const float*)d_in[4];
  const float* whh  = (const float*)d_in[5];
  const float* bih  = (const float*)d_in[6];
  const float* bhh  = (const float*)d_in[7];
  const float* wlin = (const float*)d_in[8];
  const float* blin = (const float*)d_in[9];
  float* outp = (float*)d_out;
  unsigned char* ws = (unsigned char*)d_ws;

  k_prep0<<<4, 256, 0, stream>>>(whh, ws);
  k_prep1<<<1536, 256, 0, stream>>>(whh, wlin, ws);
  k_prep2<<<1024, 256, 0, stream>>>(wih, ech, bih, bhh, ws);
  k_hist<<<128, 256, 0, stream>>>(clen, ws);
  k_scan<<<1, 64, 0, stream>>>(ws);
  k_scatter<<<128, 256, 0, stream>>>(clen, ws);
  k_main<<<256, 512, 151552, stream>>>(cidx, wemb, blin, outp, ws);
}